// Round 2
// baseline (141.702 us; speedup 1.0000x reference)
//
#include <hip/hip_runtime.h>
#include <hip/hip_bf16.h>
#include <cfloat>

// B=32, N=2048 -> BN=65536 rows, D=128, K=1024 codes
#define DIM 128
#define NCODES 1024
#define MTILE 64             // rows per block = 2 row-groups x 32 rows
#define ROWS_PER_WAVE 32
#define NSUB 2               // 16-row M-subtiles per wave
#define KSTEPS 4             // K=128 / 32
#define CODES_PER_TILE 16    // codes per half-step tile
#define NSTEPS 32            // 512 codes per half / 16
#define TILE_F16 4096        // f16 elems per 16-code tile (8 KB: hi plane 2048 + lo plane 2048)
#define TILE_BYTES 8192
#define STEP_F16 8192        // two tiles (one per code half) staged per step
#define LOSS_SCALE (12.5f / 8388608.0f)

typedef _Float16 f16x8 __attribute__((ext_vector_type(8)));
typedef float f32x4 __attribute__((ext_vector_type(4)));

// Direct global->LDS DMA, 16 B per lane. LDS dest is wave-uniform base +
// lane*16 (HW rule); global src is per-lane.
__device__ __forceinline__ void gld16(const void* g, void* l) {
    __builtin_amdgcn_global_load_lds((const __attribute__((address_space(1))) void*)g,
                                     (__attribute__((address_space(3))) void*)l, 16, 0, 0);
}

// prep: E (fp32) -> Epk (packed staging-ready f16 hi/lo image) + enorm.
// Tile g (0..63) holds 16 codes: half h = g/32 (codes h*512+...), step s = g%32,
// code = h*512 + s*16 + m16. Within a tile (f16 units):
//   addr = g*4096 + plane*2048 + ks*512 + (quad*16 + m16)*8 + j
// (ks=k>>5, quad=(k>>3)&3, j=k&7) so vq's lane l=quad*16+m16 reads its 16 B at
// base + l*16 -> conflict-free lane-linear ds_read_b128 + DMA-compatible.
__global__ __launch_bounds__(128) void prep_kernel(const float* __restrict__ E,
                                                   _Float16* __restrict__ Epk,
                                                   float* __restrict__ enorm,
                                                   float* __restrict__ loss) {
    const int k = blockIdx.x;   // code
    const int d = threadIdx.x;  // dim
    if (k == 0 && d == 0) *loss = 0.f;
    float e = E[k * DIM + d];
    _Float16 h = (_Float16)e;
    _Float16 l = (_Float16)(e - (float)h);
    const int g = (k >> 9) * 32 + ((k >> 4) & 31);
    const int m16 = k & 15;
    const int ks = d >> 5, quad = (d >> 3) & 3, j = d & 7;
    const int addr = g * TILE_F16 + ks * 512 + ((quad << 4) + m16) * 8 + j;
    Epk[addr] = h;           // hi plane
    Epk[addr + 2048] = l;    // lo plane
    float sq = e * e;
#pragma unroll
    for (int off = 32; off > 0; off >>= 1) sq += __shfl_down(sq, off, 64);
    __shared__ float s2[2];
    if ((d & 63) == 0) s2[d >> 6] = sq;
    __syncthreads();
    if (d == 0) enorm[k] = s2[0] + s2[1];
}

// Fused MFMA dist + argmin + gather + loss.
// r8 (this round): r7 killed bank conflicts + staging latency with zero gain ->
// kernel is latency/convoy-bound (all pipes <35%, 5030 cyc/step vs ~1800 of
// pipe work). Total waves was pinned at 2048 (= 8/CU) by rows/wave; the only
// way past is >1 wave per row. Split the CODE axis: waves 0,1 scan codes
// 0..511, waves 2,3 scan 512..1023, same 32-row structure; merge the two
// per-row (v,i) candidates in LDS (i0<i1 always, so strict v1<v0 == global
// first-index rule). MTILE=64, grid 1024 -> 4 blocks/CU, 16 waves/CU.
// Also folds ||E||^2 into the MFMA accumulator init (one less v_add/position).
// r3 lesson: no runtime-indexed register arrays.
__global__ __launch_bounds__(256, 4) void vq_kernel(const float* __restrict__ z,
                                                    const _Float16* __restrict__ Epk,
                                                    const float* __restrict__ enorm,
                                                    const float* __restrict__ E,
                                                    float* __restrict__ out,
                                                    float* __restrict__ loss) {
    const int t = threadIdx.x;
    const int lane = t & 63;
    const int wave = t >> 6;
    const int half = wave >> 1;  // code half: codes [half*512, half*512+512)
    const int rw = wave & 1;     // row group: rows [rw*32, rw*32+32)
    const int m16 = lane & 15;   // A row within subtile / B,C code col
    const int quad = lane >> 4;  // k-group for A/B; row-group for C

    __shared__ __attribute__((aligned(16))) _Float16 s_b[2][STEP_F16];  // 2 x 16 KB
    __shared__ __attribute__((aligned(16))) float s_enorm[NCODES];      // 4096 B
    __shared__ float s_znorm[MTILE];
    __shared__ int s_ind[MTILE];
    __shared__ float s_bv[2][MTILE];
    __shared__ int s_bi[2][MTILE];

    // enorm -> LDS via DMA (4 waves x 1024 B); drained by the first barrier.
    gld16((const char*)enorm + wave * 1024 + lane * 16, (char*)s_enorm + wave * 1024);

    // ---- A fragments: this wave's 32 rows, K=128, scaled by -2, f16 hi/lo.
    // A layout (16x16x32): lane holds A[m=lane&15][k=quad*8+j], j=0..7.
    f16x8 Ahi[NSUB][KSTEPS], Alo[NSUB][KSTEPS];
    float znp[NSUB] = {0.f, 0.f};
    const int rowbase = blockIdx.x * MTILE + rw * ROWS_PER_WAVE;
#pragma unroll
    for (int s = 0; s < NSUB; ++s) {
        const int row = rowbase + s * 16 + m16;
        const float* zp = z + (size_t)row * DIM + quad * 8;
#pragma unroll
        for (int ks = 0; ks < KSTEPS; ++ks) {
            float4 v0 = *(const float4*)(zp + ks * 32);
            float4 v1 = *(const float4*)(zp + ks * 32 + 4);
            float zv[8] = {v0.x, v0.y, v0.z, v0.w, v1.x, v1.y, v1.z, v1.w};
#pragma unroll
            for (int j = 0; j < 8; ++j) {
                znp[s] = fmaf(zv[j], zv[j], znp[s]);
                float tt = -2.f * zv[j];
                _Float16 h = (_Float16)tt;
                Ahi[s][ks][j] = h;
                Alo[s][ks][j] = (_Float16)(tt - (float)h);
            }
        }
    }
    // znorm per row -> LDS (half-0 waves write; half-1 would write identical)
#pragma unroll
    for (int s = 0; s < NSUB; ++s) {
        float v = znp[s];
        v += __shfl_xor(v, 16, 64);
        v += __shfl_xor(v, 32, 64);
        if (half == 0 && quad == 0) s_znorm[rw * ROWS_PER_WAVE + s * 16 + m16] = v;
    }

    float bestv[NSUB][4];
    int besti[NSUB][4];
#pragma unroll
    for (int s = 0; s < NSUB; ++s)
#pragma unroll
        for (int r = 0; r < 4; ++r) {
            bestv[s][r] = FLT_MAX;
            besti[s][r] = 0;
        }

    // Stage step ST's two 8 KB tiles (half0: g=ST, half1: g=32+ST) into LDS
    // buffer B via global_load_lds. 16 chunks of 1 KB; wave w DMAs 4 chunks.
    // Source carries lane*16; LDS dest is the wave-uniform chunk base.
#define STAGE(ST, B)                                                                   \
    {                                                                                  \
        const char* g0 = (const char*)Epk + (size_t)(ST)*TILE_BYTES + lane * 16;       \
        const char* g1 = (const char*)Epk + (size_t)(32 + (ST)) * TILE_BYTES + lane * 16; \
        char* lsb = (char*)s_b[B];                                                     \
        gld16(g0 + (wave + 0) * 1024, lsb + (wave + 0) * 1024);                        \
        gld16(g0 + (wave + 4) * 1024, lsb + (wave + 4) * 1024);                        \
        gld16(g1 + (wave + 0) * 1024, lsb + (wave + 8) * 1024);                        \
        gld16(g1 + (wave + 4) * 1024, lsb + (wave + 12) * 1024);                       \
    }

    STAGE(0, 0)
    __syncthreads();

    int buf = 0;
    for (int st = 0; st < NSTEPS; ++st) {
        if (st + 1 < NSTEPS) STAGE(st + 1, buf ^ 1)  // lands during compute below
        const _Float16* bb = s_b[buf] + half * TILE_F16;
        f16x8 Bh[KSTEPS], Bl[KSTEPS];
#pragma unroll
        for (int ks = 0; ks < KSTEPS; ++ks) {
            Bh[ks] = *(const f16x8*)(bb + ks * 512 + lane * 8);
            Bl[ks] = *(const f16x8*)(bb + 2048 + ks * 512 + lane * 8);
        }
        const int n = half * 512 + st * CODES_PER_TILE + m16;
        const float e = s_enorm[n];
        f32x4 acc_hh[NSUB], acc_c[NSUB];
#pragma unroll
        for (int s = 0; s < NSUB; ++s) {
            acc_hh[s] = (f32x4){e, e, e, e};  // fold ||E||^2 into accumulator
            acc_c[s] = (f32x4){0.f, 0.f, 0.f, 0.f};
        }
#pragma unroll
        for (int ks = 0; ks < KSTEPS; ++ks)
#pragma unroll
            for (int s = 0; s < NSUB; ++s) {
                acc_c[s] = __builtin_amdgcn_mfma_f32_16x16x32_f16(Ahi[s][ks], Bl[ks], acc_c[s], 0, 0, 0);
                acc_c[s] = __builtin_amdgcn_mfma_f32_16x16x32_f16(Alo[s][ks], Bh[ks], acc_c[s], 0, 0, 0);
                acc_hh[s] = __builtin_amdgcn_mfma_f32_16x16x32_f16(Ahi[s][ks], Bh[ks], acc_hh[s], 0, 0, 0);
            }
        // C layout: col = lane&15 (code), row = quad*4 + r
#pragma unroll
        for (int s = 0; s < NSUB; ++s)
#pragma unroll
            for (int r = 0; r < 4; ++r) {
                float d = acc_hh[s][r] + acc_c[s][r];
                if (d < bestv[s][r]) {  // strict <, ascending n per lane => first-index
                    bestv[s][r] = d;
                    besti[s][r] = n;
                }
            }
        __syncthreads();  // drains st+1 DMA; buf safe to overwrite at st+2
        buf ^= 1;
    }
#undef STAGE

    // ---- in-wave argmin across the 16 m16-lanes (xor butterflies stay in-quad;
    // lexicographic (v,i) merge == first-index rule within this code half)
#pragma unroll
    for (int s = 0; s < NSUB; ++s)
#pragma unroll
        for (int r = 0; r < 4; ++r) {
            float v = bestv[s][r];
            int i = besti[s][r];
#pragma unroll
            for (int m = 1; m <= 8; m <<= 1) {
                float ov = __shfl_xor(v, m, 64);
                int oi = __shfl_xor(i, m, 64);
                if (ov < v || (ov == v && oi < i)) {
                    v = ov;
                    i = oi;
                }
            }
            bestv[s][r] = v;
            besti[s][r] = i;
        }

    // winner lane per quad owns rows quad*4+r (+s*16) of its row group
    if (m16 == 0) {
#pragma unroll
        for (int s = 0; s < NSUB; ++s)
#pragma unroll
            for (int r = 0; r < 4; ++r) {
                const int row = rw * ROWS_PER_WAVE + s * 16 + quad * 4 + r;
                s_bv[half][row] = bestv[s][r];
                s_bi[half][row] = besti[s][r];
            }
    }
    __syncthreads();

    // ---- merge code halves (wave 0 only; one thread per row).
    // i0 < i1 always, so strict v1<v0 implements the global first-index rule.
    if (t < MTILE) {
        const float v0 = s_bv[0][t], v1 = s_bv[1][t];
        const int i0 = s_bi[0][t], i1 = s_bi[1][t];
        const float wv = (v1 < v0) ? v1 : v0;
        s_ind[t] = (v1 < v0) ? i1 : i0;
        float lp = s_znorm[t] + wv;  // ||z-E||^2 = ||z||^2 + dist'
#pragma unroll
        for (int m = 32; m > 0; m >>= 1) lp += __shfl_xor(lp, m, 64);
        if (t == 0) atomicAdd(loss, lp * LOSS_SCALE);
    }
    __syncthreads();

    // ---- gather-write z_q (STE forward == z_q), float4 coalesced, E is L2-hot
    const float4* E4 = (const float4*)E;
    float4* out4 = (float4*)(out + (size_t)blockIdx.x * (MTILE * DIM));
#pragma unroll
    for (int i = 0; i < (MTILE * DIM) / (256 * 4); ++i) {
        const int f = t + i * 256;  // float4 index within tile
        const int r = f >> 5;       // 32 float4 per row
        const int d = f & 31;
        out4[f] = E4[(size_t)s_ind[r] * 32 + d];
    }
}

extern "C" void kernel_launch(void* const* d_in, const int* in_sizes, int n_in,
                              void* d_out, int out_size, void* d_ws, size_t ws_size,
                              hipStream_t stream) {
    const float* z = (const float*)d_in[0];  // [BN,128] fp32
    const float* E = (const float*)d_in[1];  // [1024,128] fp32
    float* out = (float*)d_out;              // [BN*128] z_q + [1] loss
    float* loss = out + (size_t)(out_size - 1);
    _Float16* Epk = (_Float16*)d_ws;                          // 512 KB packed image
    float* enorm = (float*)((char*)d_ws + (size_t)NCODES * DIM * 2 * sizeof(_Float16));  // 4 KB
    const int BN = in_sizes[0] / DIM;

    prep_kernel<<<NCODES, 128, 0, stream>>>(E, Epk, enorm, loss);
    vq_kernel<<<BN / MTILE, 256, 0, stream>>>(z, Epk, enorm, E, out, loss);
}

// Round 3
// 139.819 us; speedup vs baseline: 1.0135x; 1.0135x over previous
//
#include <hip/hip_runtime.h>
#include <hip/hip_bf16.h>
#include <cfloat>

// B=32, N=2048 -> BN=65536 rows, D=128, K=1024 codes
#define DIM 128
#define NCODES 1024
#define MTILE 64             // rows per block = 2 row-groups x 32 rows
#define ROWS_PER_WAVE 32
#define NSUB 2               // 16-row M-subtiles per wave
#define KSTEPS 4             // K=128 / 32
#define CODES_PER_TILE 16    // codes per half-step tile
#define NSTEPS 32            // 512 codes per half / 16
#define TILE_F16 4096        // f16 elems per 16-code tile (8 KB: hi 2048 + lo 2048)
#define TILE_BYTES 8192
#define STEP_F16 8192        // two tiles (one per code half) staged per step
#define LOSS_SCALE (12.5f / 8388608.0f)

typedef _Float16 f16x8 __attribute__((ext_vector_type(8)));
typedef float f32x4 __attribute__((ext_vector_type(4)));

// Direct global->LDS DMA, 16 B per lane. LDS dest is wave-uniform base +
// lane*16 (HW rule); global src is per-lane.
__device__ __forceinline__ void gld16(const void* g, void* l) {
    __builtin_amdgcn_global_load_lds((const __attribute__((address_space(1))) void*)g,
                                     (__attribute__((address_space(3))) void*)l, 16, 0, 0);
}

// prep: E (fp32) -> Epk (packed staging-ready f16 hi/lo image) + enorm.
// Tile g (0..63) holds 16 codes: half h = g/32, step s = g%32,
// code = h*512 + s*16 + m16. Within a tile (f16 units):
//   addr = g*4096 + plane*2048 + ks*512 + (quad*16 + m16)*8 + j
// so vq's lane l=quad*16+m16 reads its 16 B at base + l*16 -> conflict-free
// lane-linear ds_read_b128 + DMA-compatible. Block 0 zeroes loss.
__global__ __launch_bounds__(128) void prep_kernel(const float* __restrict__ E,
                                                   _Float16* __restrict__ Epk,
                                                   float* __restrict__ enorm,
                                                   float* __restrict__ loss) {
    const int k = blockIdx.x;   // code
    const int d = threadIdx.x;  // dim
    if (k == 0 && d == 0) *loss = 0.f;
    float e = E[k * DIM + d];
    _Float16 h = (_Float16)e;
    _Float16 l = (_Float16)(e - (float)h);
    const int g = (k >> 9) * 32 + ((k >> 4) & 31);
    const int m16 = k & 15;
    const int ks = d >> 5, quad = (d >> 3) & 3, j = d & 7;
    const int addr = g * TILE_F16 + ks * 512 + ((quad << 4) + m16) * 8 + j;
    Epk[addr] = h;           // hi plane
    Epk[addr + 2048] = l;    // lo plane
    float sq = e * e;
#pragma unroll
    for (int off = 32; off > 0; off >>= 1) sq += __shfl_down(sq, off, 64);
    __shared__ float s2[2];
    if ((d & 63) == 0) s2[d >> 6] = sq;
    __syncthreads();
    if (d == 0) enorm[k] = s2[0] + s2[1];
}

// Fused MFMA dist + argmin + gather + loss.
// r9 (this round): r8 doubled occupancy with zero gain -> the convoy is the
// per-step phase lockstep, not wave count: barrier -> ds_read(wait) ->
// MFMA(dep) -> argmin(dep) -> barrier makes the LDS/MFMA/VALU pipes run
// SEQUENTIALLY (1536+512+1862+~900+drain = 5300 cyc/step ~= measured).
// Fix: register-prefetch B fragments one step ahead -> ds_read(st+1),
// MFMA(st), argmin(st) are mutually independent within a step; compiler
// interleaves; step -> max(pipe) not sum. Frags consumed one step after
// staging => 2 LDS buffers carry a 2-step-ahead DMA pipeline. s_enorm
// dropped (e prefetched from L2-resident global); acc_hh/acc_c merged,
// init {e} (saves 8 movs + 8 adds/step; fp32 order change only).
// r3 lesson: no runtime-indexed register arrays (loop unrolled x2 with
// named FA/FB fragment sets).
__global__ __launch_bounds__(256, 3) void vq_kernel(const float* __restrict__ z,
                                                    const _Float16* __restrict__ Epk,
                                                    const float* __restrict__ enorm,
                                                    const float* __restrict__ E,
                                                    float* __restrict__ out,
                                                    float* __restrict__ loss) {
    const int t = threadIdx.x;
    const int lane = t & 63;
    const int wave = t >> 6;
    const int half = wave >> 1;  // code half: codes [half*512, half*512+512)
    const int rw = wave & 1;     // row group: rows [rw*32, rw*32+32)
    const int m16 = lane & 15;   // A row within subtile / B,C code col
    const int quad = lane >> 4;  // k-group for A/B; row-group for C

    __shared__ __attribute__((aligned(16))) _Float16 s_b[2][STEP_F16];  // 2 x 16 KB
    __shared__ float s_znorm[MTILE];
    __shared__ int s_ind[MTILE];
    __shared__ float s_bv[2][MTILE];
    __shared__ int s_bi[2][MTILE];

    // Stage step ST's two 8 KB tiles (half0: g=ST, half1: g=32+ST) into LDS
    // buffer P via global_load_lds. 16 chunks of 1 KB; wave w DMAs 4 chunks.
#define STAGE(ST, P)                                                                      \
    {                                                                                     \
        const char* g0 = (const char*)Epk + (size_t)(ST)*TILE_BYTES + lane * 16;          \
        const char* g1 = (const char*)Epk + (size_t)(32 + (ST)) * TILE_BYTES + lane * 16; \
        char* lsb = (char*)s_b[P];                                                        \
        gld16(g0 + (wave + 0) * 1024, lsb + (wave + 0) * 1024);                           \
        gld16(g0 + (wave + 4) * 1024, lsb + (wave + 4) * 1024);                           \
        gld16(g1 + (wave + 0) * 1024, lsb + (wave + 8) * 1024);                           \
        gld16(g1 + (wave + 4) * 1024, lsb + (wave + 12) * 1024);                          \
    }

    // Issue first two step-tiles immediately; their latency hides under A-prep.
    STAGE(0, 0)
    STAGE(1, 1)

    // ---- A fragments: this wave's 32 rows, K=128, scaled by -2, f16 hi/lo.
    // A layout (16x16x32): lane holds A[m=lane&15][k=quad*8+j], j=0..7.
    f16x8 Ahi[NSUB][KSTEPS], Alo[NSUB][KSTEPS];
    float znp[NSUB] = {0.f, 0.f};
    const int rowbase = blockIdx.x * MTILE + rw * ROWS_PER_WAVE;
#pragma unroll
    for (int s = 0; s < NSUB; ++s) {
        const int row = rowbase + s * 16 + m16;
        const float* zp = z + (size_t)row * DIM + quad * 8;
#pragma unroll
        for (int ks = 0; ks < KSTEPS; ++ks) {
            float4 v0 = *(const float4*)(zp + ks * 32);
            float4 v1 = *(const float4*)(zp + ks * 32 + 4);
            float zv[8] = {v0.x, v0.y, v0.z, v0.w, v1.x, v1.y, v1.z, v1.w};
#pragma unroll
            for (int j = 0; j < 8; ++j) {
                znp[s] = fmaf(zv[j], zv[j], znp[s]);
                float tt = -2.f * zv[j];
                _Float16 h = (_Float16)tt;
                Ahi[s][ks][j] = h;
                Alo[s][ks][j] = (_Float16)(tt - (float)h);
            }
        }
    }
    // znorm per row -> LDS (half-0 waves write; half-1 would write identical)
#pragma unroll
    for (int s = 0; s < NSUB; ++s) {
        float v = znp[s];
        v += __shfl_xor(v, 16, 64);
        v += __shfl_xor(v, 32, 64);
        if (half == 0 && quad == 0) s_znorm[rw * ROWS_PER_WAVE + s * 16 + m16] = v;
    }

    float bestv[NSUB][4];
    int besti[NSUB][4];
#pragma unroll
    for (int s = 0; s < NSUB; ++s)
#pragma unroll
        for (int r = 0; r < 4; ++r) {
            bestv[s][r] = FLT_MAX;
            besti[s][r] = 0;
        }

    const float* ep = enorm + half * 512 + m16;  // e(st) = ep[st*16], L2-hot

    __syncthreads();  // drains STAGE(0),STAGE(1) DMAs (vmcnt0) for all waves

    // Prologue frag read: F(0) from s_b[0]
    f16x8 FAh[KSTEPS], FAl[KSTEPS], FBh[KSTEPS], FBl[KSTEPS];
    float eA, eB = 0.f;
    {
        const _Float16* bb = s_b[0] + half * TILE_F16;
#pragma unroll
        for (int ks = 0; ks < KSTEPS; ++ks) {
            FAh[ks] = *(const f16x8*)(bb + ks * 512 + lane * 8);
            FAl[ks] = *(const f16x8*)(bb + 2048 + ks * 512 + lane * 8);
        }
        eA = ep[0];
    }
    __syncthreads();  // prologue reads of s_b[0] done before STAGE(2,0) below

    // Step body: uses frags/e (CH,CL,CE); prefetches st+1 into (NH,NL,NE).
    // PCUR = buffer F(ST) came from (free to re-stage), PNXT = buffer holding
    // F(ST+1) (staged at ST-1, drained by the barrier that ended ST-1).
#define BODY(ST, CH, CL, CE, NH, NL, NE, PCUR, PNXT)                                \
    {                                                                               \
        if ((ST) + 2 < NSTEPS) STAGE((ST) + 2, PCUR)                                \
        if ((ST) + 1 < NSTEPS) {                                                    \
            const _Float16* bb = s_b[PNXT] + half * TILE_F16;                       \
            _Pragma("unroll") for (int ks = 0; ks < KSTEPS; ++ks) {                 \
                NH[ks] = *(const f16x8*)(bb + ks * 512 + lane * 8);                 \
                NL[ks] = *(const f16x8*)(bb + 2048 + ks * 512 + lane * 8);          \
            }                                                                       \
            NE = ep[((ST) + 1) * CODES_PER_TILE];                                   \
        }                                                                           \
        f32x4 acc0 = {CE, CE, CE, CE}, acc1 = {CE, CE, CE, CE};                     \
        _Pragma("unroll") for (int ks = 0; ks < KSTEPS; ++ks) {                     \
            acc0 = __builtin_amdgcn_mfma_f32_16x16x32_f16(Ahi[0][ks], CH[ks], acc0, 0, 0, 0); \
            acc1 = __builtin_amdgcn_mfma_f32_16x16x32_f16(Ahi[1][ks], CH[ks], acc1, 0, 0, 0); \
            acc0 = __builtin_amdgcn_mfma_f32_16x16x32_f16(Ahi[0][ks], CL[ks], acc0, 0, 0, 0); \
            acc1 = __builtin_amdgcn_mfma_f32_16x16x32_f16(Ahi[1][ks], CL[ks], acc1, 0, 0, 0); \
            acc0 = __builtin_amdgcn_mfma_f32_16x16x32_f16(Alo[0][ks], CH[ks], acc0, 0, 0, 0); \
            acc1 = __builtin_amdgcn_mfma_f32_16x16x32_f16(Alo[1][ks], CH[ks], acc1, 0, 0, 0); \
        }                                                                           \
        const int n = half * 512 + (ST)*CODES_PER_TILE + m16;                       \
        /* C layout: col = lane&15 (code), row = quad*4 + r */                      \
        _Pragma("unroll") for (int r = 0; r < 4; ++r) {                             \
            if (acc0[r] < bestv[0][r]) { bestv[0][r] = acc0[r]; besti[0][r] = n; }  \
            if (acc1[r] < bestv[1][r]) { bestv[1][r] = acc1[r]; besti[1][r] = n; }  \
        }                                                                           \
        __syncthreads(); /* drains STAGE(ST+2); next step may read s_b[PNXT] */     \
    }

    for (int it = 0; it < NSTEPS / 2; ++it) {
        const int st0 = 2 * it;
        BODY(st0, FAh, FAl, eA, FBh, FBl, eB, 0, 1)
        BODY(st0 + 1, FBh, FBl, eB, FAh, FAl, eA, 1, 0)
    }
#undef BODY
#undef STAGE

    // ---- in-wave argmin across the 16 m16-lanes (xor butterflies stay in-quad;
    // lexicographic (v,i) merge == first-index rule within this code half)
#pragma unroll
    for (int s = 0; s < NSUB; ++s)
#pragma unroll
        for (int r = 0; r < 4; ++r) {
            float v = bestv[s][r];
            int i = besti[s][r];
#pragma unroll
            for (int m = 1; m <= 8; m <<= 1) {
                float ov = __shfl_xor(v, m, 64);
                int oi = __shfl_xor(i, m, 64);
                if (ov < v || (ov == v && oi < i)) {
                    v = ov;
                    i = oi;
                }
            }
            bestv[s][r] = v;
            besti[s][r] = i;
        }

    // winner lane per quad owns rows quad*4+r (+s*16) of its row group
    if (m16 == 0) {
#pragma unroll
        for (int s = 0; s < NSUB; ++s)
#pragma unroll
            for (int r = 0; r < 4; ++r) {
                const int row = rw * ROWS_PER_WAVE + s * 16 + quad * 4 + r;
                s_bv[half][row] = bestv[s][r];
                s_bi[half][row] = besti[s][r];
            }
    }
    __syncthreads();

    // ---- merge code halves (wave 0 only; one thread per row).
    // i0 < i1 always, so strict v1<v0 implements the global first-index rule.
    if (t < MTILE) {
        const float v0 = s_bv[0][t], v1 = s_bv[1][t];
        const int i0 = s_bi[0][t], i1 = s_bi[1][t];
        const float wv = (v1 < v0) ? v1 : v0;
        s_ind[t] = (v1 < v0) ? i1 : i0;
        float lp = s_znorm[t] + wv;  // ||z-E||^2 = ||z||^2 + dist'
#pragma unroll
        for (int m = 32; m > 0; m >>= 1) lp += __shfl_xor(lp, m, 64);
        if (t == 0) atomicAdd(loss, lp * LOSS_SCALE);
    }
    __syncthreads();

    // ---- gather-write z_q (STE forward == z_q), float4 coalesced, E is L2-hot
    const float4* E4 = (const float4*)E;
    float4* out4 = (float4*)(out + (size_t)blockIdx.x * (MTILE * DIM));
#pragma unroll
    for (int i = 0; i < (MTILE * DIM) / (256 * 4); ++i) {
        const int f = t + i * 256;  // float4 index within tile
        const int r = f >> 5;       // 32 float4 per row
        const int d = f & 31;
        out4[f] = E4[(size_t)s_ind[r] * 32 + d];
    }
}

extern "C" void kernel_launch(void* const* d_in, const int* in_sizes, int n_in,
                              void* d_out, int out_size, void* d_ws, size_t ws_size,
                              hipStream_t stream) {
    const float* z = (const float*)d_in[0];  // [BN,128] fp32
    const float* E = (const float*)d_in[1];  // [1024,128] fp32
    float* out = (float*)d_out;              // [BN*128] z_q + [1] loss
    float* loss = out + (size_t)(out_size - 1);
    _Float16* Epk = (_Float16*)d_ws;                          // 512 KB packed image
    float* enorm = (float*)((char*)d_ws + (size_t)NCODES * DIM * 2 * sizeof(_Float16));  // 4 KB
    const int BN = in_sizes[0] / DIM;

    prep_kernel<<<NCODES, 128, 0, stream>>>(E, Epk, enorm, loss);
    vq_kernel<<<BN / MTILE, 256, 0, stream>>>(z, Epk, enorm, E, out, loss);
}

// Round 4
// 135.551 us; speedup vs baseline: 1.0454x; 1.0315x over previous
//
#include <hip/hip_runtime.h>
#include <hip/hip_bf16.h>
#include <cfloat>

// B=32, N=2048 -> BN=65536 rows, D=128, K=1024 codes
#define DIM 128
#define NCODES 1024
#define MTILE 64             // rows per block = 2 row-groups x 32 rows
#define ROWS_PER_WAVE 32
#define NSUB 2               // 16-row M-subtiles per wave
#define KSTEPS 4             // K=128 / 32
#define CODES_PER_TILE 16    // codes per half-step tile
#define NSTEPS 32            // 512 codes per half / 16
#define TILE_F16 4096        // f16 elems per 16-code tile (8 KB: hi 2048 + lo 2048)
#define TILE_BYTES 8192
#define STEP_F16 8192        // two tiles (one per code half) staged per step
#define LOSS_SCALE (12.5f / 8388608.0f)

typedef _Float16 f16x8 __attribute__((ext_vector_type(8)));
typedef float f32x4 __attribute__((ext_vector_type(4)));

// Direct global->LDS DMA, 16 B per lane. LDS dest is wave-uniform base +
// lane*16 (HW rule); global src is per-lane.
__device__ __forceinline__ void gld16(const void* g, void* l) {
    __builtin_amdgcn_global_load_lds((const __attribute__((address_space(1))) void*)g,
                                     (__attribute__((address_space(3))) void*)l, 16, 0, 0);
}

// prep: E (fp32) -> Epk (packed staging-ready f16 hi/lo image) + enorm.
// Tile g (0..63) holds 16 codes: half h = g/32, step s = g%32,
// code = h*512 + s*16 + m16. Within a tile (f16 units):
//   addr = g*4096 + plane*2048 + ks*512 + (quad*16 + m16)*8 + j
// so vq's lane l=quad*16+m16 reads its 16 B at base + l*16 -> conflict-free
// lane-linear ds_read_b128 + DMA-compatible. Block 0 zeroes loss.
__global__ __launch_bounds__(128) void prep_kernel(const float* __restrict__ E,
                                                   _Float16* __restrict__ Epk,
                                                   float* __restrict__ enorm,
                                                   float* __restrict__ loss) {
    const int k = blockIdx.x;   // code
    const int d = threadIdx.x;  // dim
    if (k == 0 && d == 0) *loss = 0.f;
    float e = E[k * DIM + d];
    _Float16 h = (_Float16)e;
    _Float16 l = (_Float16)(e - (float)h);
    const int g = (k >> 9) * 32 + ((k >> 4) & 31);
    const int m16 = k & 15;
    const int ks = d >> 5, quad = (d >> 3) & 3, j = d & 7;
    const int addr = g * TILE_F16 + ks * 512 + ((quad << 4) + m16) * 8 + j;
    Epk[addr] = h;           // hi plane
    Epk[addr + 2048] = l;    // lo plane
    float sq = e * e;
#pragma unroll
    for (int off = 32; off > 0; off >>= 1) sq += __shfl_down(sq, off, 64);
    __shared__ float s2[2];
    if ((d & 63) == 0) s2[d >> 6] = sq;
    __syncthreads();
    if (d == 0) enorm[k] = s2[0] + s2[1];
}

// Fused MFMA dist + argmin + gather + loss.
// r10 (this round): r7/r8/r9 each fixed a real inefficiency (conflicts,
// occupancy, read-pipelining) with ZERO time delta -> this is m233's 2-phase
// signature: 51.5 GFLOP/66us = 780 TF = 37.6% of the 16x16 ceiling, exactly
// the m97-structure ceiling. Cause: consume-distance 1 forces the pre-barrier
// drain to vmcnt(0) every step (T4's measured -38..-73%). Fix = T3+T4+T5:
// 3 LDS buffers, stage 3 tiles ahead, raw s_barrier with COUNTED
// "s_waitcnt vmcnt(4)" (the batch issued this step rides across the barrier;
// the protected batch had a full step to land), lgkmcnt(0) for cross-wave LDS
// read/overwrite safety, s_setprio(1) around the MFMA cluster. In-loop VMEM is
// exactly 4 gld16/step (e back in s_enorm LDS, free broadcast read).
// Hazards: buf X tile T read @step T-1 (lgkm-drained pre-barrier), restaged
// (tile T+3) @step T post-barrier; tail steps 29..31 get vmcnt(0)/no-stage.
// r3 lesson: no runtime-indexed register arrays (period-6 unroll, literal ST).
__global__ __launch_bounds__(256, 2) void vq_kernel(const float* __restrict__ z,
                                                    const _Float16* __restrict__ Epk,
                                                    const float* __restrict__ enorm,
                                                    const float* __restrict__ E,
                                                    float* __restrict__ out,
                                                    float* __restrict__ loss) {
    const int t = threadIdx.x;
    const int lane = t & 63;
    const int wave = t >> 6;
    const int half = wave >> 1;  // code half: codes [half*512, half*512+512)
    const int rw = wave & 1;     // row group: rows [rw*32, rw*32+32)
    const int m16 = lane & 15;   // A row within subtile / B,C code col
    const int quad = lane >> 4;  // k-group for A/B; row-group for C

    __shared__ __attribute__((aligned(16))) _Float16 s_b[3][STEP_F16];  // 3 x 16 KB
    __shared__ __attribute__((aligned(16))) float s_enorm[NCODES];      // 4 KB
    __shared__ float s_znorm[MTILE];
    __shared__ int s_ind[MTILE];
    __shared__ float s_bv[2][MTILE];
    __shared__ int s_bi[2][MTILE];

#define LGKM0 asm volatile("s_waitcnt lgkmcnt(0)" ::: "memory")
#define VM(N) asm volatile("s_waitcnt vmcnt(" #N ")" ::: "memory")
#define BAR __builtin_amdgcn_s_barrier()

    // Stage step ST's two 8 KB tiles (half0: g=ST, half1: g=32+ST) into LDS
    // buffer P via global_load_lds. 16 chunks of 1 KB; wave w DMAs 4 chunks.
#define STAGE(ST, P)                                                                      \
    {                                                                                     \
        const char* g0 = (const char*)Epk + (size_t)(ST)*TILE_BYTES + lane * 16;          \
        const char* g1 = (const char*)Epk + (size_t)(32 + (ST)) * TILE_BYTES + lane * 16; \
        char* lsb = (char*)s_b[P];                                                        \
        gld16(g0 + (wave + 0) * 1024, lsb + (wave + 0) * 1024);                           \
        gld16(g0 + (wave + 4) * 1024, lsb + (wave + 4) * 1024);                           \
        gld16(g1 + (wave + 0) * 1024, lsb + (wave + 8) * 1024);                           \
        gld16(g1 + (wave + 4) * 1024, lsb + (wave + 12) * 1024);                          \
    }

    // enorm -> LDS (4 waves x 1024 B) + first three step-tiles; latency hides
    // under A-prep. All drained by the prologue __syncthreads.
    gld16((const char*)enorm + wave * 1024 + lane * 16, (char*)s_enorm + wave * 1024);
    STAGE(0, 0)
    STAGE(1, 1)
    STAGE(2, 2)

    // ---- A fragments: this wave's 32 rows, K=128, scaled by -2, f16 hi/lo.
    // A layout (16x16x32): lane holds A[m=lane&15][k=quad*8+j], j=0..7.
    f16x8 Ahi[NSUB][KSTEPS], Alo[NSUB][KSTEPS];
    float znp[NSUB] = {0.f, 0.f};
    const int rowbase = blockIdx.x * MTILE + rw * ROWS_PER_WAVE;
#pragma unroll
    for (int s = 0; s < NSUB; ++s) {
        const int row = rowbase + s * 16 + m16;
        const float* zp = z + (size_t)row * DIM + quad * 8;
#pragma unroll
        for (int ks = 0; ks < KSTEPS; ++ks) {
            float4 v0 = *(const float4*)(zp + ks * 32);
            float4 v1 = *(const float4*)(zp + ks * 32 + 4);
            float zv[8] = {v0.x, v0.y, v0.z, v0.w, v1.x, v1.y, v1.z, v1.w};
#pragma unroll
            for (int j = 0; j < 8; ++j) {
                znp[s] = fmaf(zv[j], zv[j], znp[s]);
                float tt = -2.f * zv[j];
                _Float16 h = (_Float16)tt;
                Ahi[s][ks][j] = h;
                Alo[s][ks][j] = (_Float16)(tt - (float)h);
            }
        }
    }
    // znorm per row -> LDS (half-0 waves write; half-1 would write identical)
#pragma unroll
    for (int s = 0; s < NSUB; ++s) {
        float v = znp[s];
        v += __shfl_xor(v, 16, 64);
        v += __shfl_xor(v, 32, 64);
        if (half == 0 && quad == 0) s_znorm[rw * ROWS_PER_WAVE + s * 16 + m16] = v;
    }

    float bestv[NSUB][4];
    int besti[NSUB][4];
#pragma unroll
    for (int s = 0; s < NSUB; ++s)
#pragma unroll
        for (int r = 0; r < 4; ++r) {
            bestv[s][r] = FLT_MAX;
            besti[s][r] = 0;
        }

    __syncthreads();  // full drain: tiles 0..2 + s_enorm landed, s_znorm visible

    // Prologue frag read: F(0) from s_b[0]
    f16x8 FAh[KSTEPS], FAl[KSTEPS], FBh[KSTEPS], FBl[KSTEPS];
    float eA, eB = 0.f;
    {
        const _Float16* bb = s_b[0] + half * TILE_F16;
#pragma unroll
        for (int ks = 0; ks < KSTEPS; ++ks) {
            FAh[ks] = *(const f16x8*)(bb + ks * 512 + lane * 8);
            FAl[ks] = *(const f16x8*)(bb + 2048 + ks * 512 + lane * 8);
        }
        eA = s_enorm[half * 512 + m16];
    }
    LGKM0;  // all waves' F(0) reads done before BODY(0) restages buf0 (tile 3)
    BAR;

    // Step body: stage ST+3 into SBUF=(ST%3); prefetch F(ST+1)+e from
    // RBUF=((ST+1)%3); 24 MFMA on current frags; argmin. End-of-step sync is
    // appended at the call site: VM(4);LGKM0;BAR (VM(0) at ST=29, none after).
#define BODY(ST, CH, CL, CE, NH, NL, NE, SBUF, RBUF, DO_STAGE, DO_NEXT)                       \
    {                                                                                         \
        if (DO_STAGE) STAGE((ST) + 3, SBUF)                                                   \
        if (DO_NEXT) {                                                                        \
            const _Float16* bb = s_b[RBUF] + half * TILE_F16;                                 \
            _Pragma("unroll") for (int ks = 0; ks < KSTEPS; ++ks) {                           \
                NH[ks] = *(const f16x8*)(bb + ks * 512 + lane * 8);                           \
                NL[ks] = *(const f16x8*)(bb + 2048 + ks * 512 + lane * 8);                    \
            }                                                                                 \
            NE = s_enorm[half * 512 + ((ST) + 1) * CODES_PER_TILE + m16];                     \
        }                                                                                     \
        f32x4 acc0 = {CE, CE, CE, CE}, acc1 = {CE, CE, CE, CE};                               \
        __builtin_amdgcn_s_setprio(1);                                                        \
        _Pragma("unroll") for (int ks = 0; ks < KSTEPS; ++ks) {                               \
            acc0 = __builtin_amdgcn_mfma_f32_16x16x32_f16(Ahi[0][ks], CH[ks], acc0, 0, 0, 0); \
            acc1 = __builtin_amdgcn_mfma_f32_16x16x32_f16(Ahi[1][ks], CH[ks], acc1, 0, 0, 0); \
            acc0 = __builtin_amdgcn_mfma_f32_16x16x32_f16(Ahi[0][ks], CL[ks], acc0, 0, 0, 0); \
            acc1 = __builtin_amdgcn_mfma_f32_16x16x32_f16(Ahi[1][ks], CL[ks], acc1, 0, 0, 0); \
            acc0 = __builtin_amdgcn_mfma_f32_16x16x32_f16(Alo[0][ks], CH[ks], acc0, 0, 0, 0); \
            acc1 = __builtin_amdgcn_mfma_f32_16x16x32_f16(Alo[1][ks], CH[ks], acc1, 0, 0, 0); \
        }                                                                                     \
        __builtin_amdgcn_s_setprio(0);                                                        \
        const int n_ = half * 512 + (ST)*CODES_PER_TILE + m16;                                \
        /* C layout: col = lane&15 (code), row = quad*4 + r */                                \
        _Pragma("unroll") for (int r = 0; r < 4; ++r) {                                       \
            if (acc0[r] < bestv[0][r]) { bestv[0][r] = acc0[r]; besti[0][r] = n_; }           \
            if (acc1[r] < bestv[1][r]) { bestv[1][r] = acc1[r]; besti[1][r] = n_; }           \
        }                                                                                     \
    }

    for (int it = 0; it < 4; ++it) {
        const int base = it * 6;
        BODY(base + 0, FAh, FAl, eA, FBh, FBl, eB, 0, 1, 1, 1); VM(4); LGKM0; BAR;
        BODY(base + 1, FBh, FBl, eB, FAh, FAl, eA, 1, 2, 1, 1); VM(4); LGKM0; BAR;
        BODY(base + 2, FAh, FAl, eA, FBh, FBl, eB, 2, 0, 1, 1); VM(4); LGKM0; BAR;
        BODY(base + 3, FBh, FBl, eB, FAh, FAl, eA, 0, 1, 1, 1); VM(4); LGKM0; BAR;
        BODY(base + 4, FAh, FAl, eA, FBh, FBl, eB, 1, 2, 1, 1); VM(4); LGKM0; BAR;
        BODY(base + 5, FBh, FBl, eB, FAh, FAl, eA, 2, 0, 1, 1); VM(4); LGKM0; BAR;
    }
    // tail: steps 24..31 (literal ST; staging stops at 28, counted waits end 29)
    BODY(24, FAh, FAl, eA, FBh, FBl, eB, 0, 1, 1, 1); VM(4); LGKM0; BAR;
    BODY(25, FBh, FBl, eB, FAh, FAl, eA, 1, 2, 1, 1); VM(4); LGKM0; BAR;
    BODY(26, FAh, FAl, eA, FBh, FBl, eB, 2, 0, 1, 1); VM(4); LGKM0; BAR;
    BODY(27, FBh, FBl, eB, FAh, FAl, eA, 0, 1, 1, 1); VM(4); LGKM0; BAR;
    BODY(28, FAh, FAl, eA, FBh, FBl, eB, 1, 2, 1, 1); VM(4); LGKM0; BAR;
    BODY(29, FBh, FBl, eB, FAh, FAl, eA, 2, 0, 0, 1); VM(0); LGKM0; BAR;
    BODY(30, FAh, FAl, eA, FBh, FBl, eB, 0, 1, 0, 1);  // reads F(31); no sync needed after
    BODY(31, FBh, FBl, eB, FAh, FAl, eA, 0, 0, 0, 0);
#undef BODY
#undef STAGE

    // ---- in-wave argmin across the 16 m16-lanes (xor butterflies stay in-quad;
    // lexicographic (v,i) merge == first-index rule within this code half)
#pragma unroll
    for (int s = 0; s < NSUB; ++s)
#pragma unroll
        for (int r = 0; r < 4; ++r) {
            float v = bestv[s][r];
            int i = besti[s][r];
#pragma unroll
            for (int m = 1; m <= 8; m <<= 1) {
                float ov = __shfl_xor(v, m, 64);
                int oi = __shfl_xor(i, m, 64);
                if (ov < v || (ov == v && oi < i)) {
                    v = ov;
                    i = oi;
                }
            }
            bestv[s][r] = v;
            besti[s][r] = i;
        }

    // winner lane per quad owns rows quad*4+r (+s*16) of its row group
    if (m16 == 0) {
#pragma unroll
        for (int s = 0; s < NSUB; ++s)
#pragma unroll
            for (int r = 0; r < 4; ++r) {
                const int row = rw * ROWS_PER_WAVE + s * 16 + quad * 4 + r;
                s_bv[half][row] = bestv[s][r];
                s_bi[half][row] = besti[s][r];
            }
    }
    __syncthreads();

    // ---- merge code halves (wave 0 only; one thread per row).
    // i0 < i1 always, so strict v1<v0 implements the global first-index rule.
    if (t < MTILE) {
        const float v0 = s_bv[0][t], v1 = s_bv[1][t];
        const int i0 = s_bi[0][t], i1 = s_bi[1][t];
        const float wv = (v1 < v0) ? v1 : v0;
        s_ind[t] = (v1 < v0) ? i1 : i0;
        float lp = s_znorm[t] + wv;  // ||z-E||^2 = ||z||^2 + dist'
#pragma unroll
        for (int m = 32; m > 0; m >>= 1) lp += __shfl_xor(lp, m, 64);
        if (t == 0) atomicAdd(loss, lp * LOSS_SCALE);
    }
    __syncthreads();

    // ---- gather-write z_q (STE forward == z_q), float4 coalesced, E is L2-hot
    const float4* E4 = (const float4*)E;
    float4* out4 = (float4*)(out + (size_t)blockIdx.x * (MTILE * DIM));
#pragma unroll
    for (int i = 0; i < (MTILE * DIM) / (256 * 4); ++i) {
        const int f = t + i * 256;  // float4 index within tile
        const int r = f >> 5;       // 32 float4 per row
        const int d = f & 31;
        out4[f] = E4[(size_t)s_ind[r] * 32 + d];
    }
#undef LGKM0
#undef VM
#undef BAR
}

extern "C" void kernel_launch(void* const* d_in, const int* in_sizes, int n_in,
                              void* d_out, int out_size, void* d_ws, size_t ws_size,
                              hipStream_t stream) {
    const float* z = (const float*)d_in[0];  // [BN,128] fp32
    const float* E = (const float*)d_in[1];  // [1024,128] fp32
    float* out = (float*)d_out;              // [BN*128] z_q + [1] loss
    float* loss = out + (size_t)(out_size - 1);
    _Float16* Epk = (_Float16*)d_ws;                          // 512 KB packed image
    float* enorm = (float*)((char*)d_ws + (size_t)NCODES * DIM * 2 * sizeof(_Float16));  // 4 KB
    const int BN = in_sizes[0] / DIM;

    prep_kernel<<<NCODES, 128, 0, stream>>>(E, Epk, enorm, loss);
    vq_kernel<<<BN / MTILE, 256, 0, stream>>>(z, Epk, enorm, E, out, loss);
}

// Round 5
// 131.750 us; speedup vs baseline: 1.0755x; 1.0288x over previous
//
#include <hip/hip_runtime.h>
#include <hip/hip_bf16.h>
#include <cfloat>

// B=32, N=2048 -> BN=65536 rows, D=128, K=1024 codes
#define DIM 128
#define NCODES 1024
#define MTILE 128            // rows per block = 4 waves x 32 rows
#define ROWS_PER_WAVE 32
#define NSUB 2               // 16-row M-subtiles per wave
#define KSTEPS 4             // K=128 / 32
#define CODES_PER_TILE 16    // codes per step tile
#define NSTEPS 64            // 1024 codes / 16
#define TILE_F16 4096        // f16 elems per 16-code tile (8 KB: hi 2048 + lo 2048)
#define TILE_BYTES 8192
#define LOSS_SCALE (12.5f / 8388608.0f)

typedef _Float16 f16x8 __attribute__((ext_vector_type(8)));
typedef float f32x4 __attribute__((ext_vector_type(4)));

// prep: E (fp32) -> Epk (packed fragment-linear f16 hi/lo image) + enorm.
// Tile g = k>>4 holds codes g*16..g*16+15. Within a tile (f16 units):
//   addr = g*4096 + plane*2048 + ks*512 + (quad*16 + m16)*8 + j
// (ks=d>>5, quad=(d>>3)&3, j=d&7) so vq's lane l=quad*16+m16 loads its 16 B at
// tile_base + plane*4096B + ks*1024B + l*16 -> one contiguous, coalesced 1 KB
// global_load_dwordx4 per (plane,ks). Block 0 zeroes loss.
__global__ __launch_bounds__(128) void prep_kernel(const float* __restrict__ E,
                                                   _Float16* __restrict__ Epk,
                                                   float* __restrict__ enorm,
                                                   float* __restrict__ loss) {
    const int k = blockIdx.x;   // code
    const int d = threadIdx.x;  // dim
    if (k == 0 && d == 0) *loss = 0.f;
    float e = E[k * DIM + d];
    _Float16 h = (_Float16)e;
    _Float16 l = (_Float16)(e - (float)h);
    const int g = k >> 4;
    const int m16 = k & 15;
    const int ks = d >> 5, quad = (d >> 3) & 3, j = d & 7;
    const int addr = g * TILE_F16 + ks * 512 + ((quad << 4) + m16) * 8 + j;
    Epk[addr] = h;           // hi plane
    Epk[addr + 2048] = l;    // lo plane
    float sq = e * e;
#pragma unroll
    for (int off = 32; off > 0; off >>= 1) sq += __shfl_down(sq, off, 64);
    __shared__ float s2[2];
    if ((d & 63) == 0) s2[d >> 6] = sq;
    __syncthreads();
    if (d == 0) enorm[k] = s2[0] + s2[1];
}

// Fused MFMA dist + argmin + gather + loss.
// r11 (this round): r7-r10 fixed conflicts, occupancy, read-prefetch, and
// counted-vmcnt -- all neutral at ~67 us. Whole-kernel accounting: pipe work
// sums to ~110k cyc/CU vs 160k measured -> full pipe serialization PLUS ~50k
// of barrier/drain stall. The invariant across r6-r10 is the LDS round-trip
// + per-step barrier lockstep for a codebook that is only 512 KB packed --
// i.e. L2-fits 8x over (guide common-mistake #7 / m169: don't stage
// L2-resident data). So: B fragments now stream from Epk straight into the
// r9-style register double-buffer via contiguous 1 KB global_load_dwordx4
// (packed layout makes them sequential; r6's streaming wall came from the
// old scattered layout). ZERO barriers in the main loop -> waves free-run
// and drift, pipes overlap instead of phase-locking; LDS DMA writes gone.
// Code-halving dropped (occupancy proven irrelevant in r8): each wave owns
// 32 rows x all 1024 codes; znorm stays in registers (shfl at the end).
// LDS: 4.6 KB (enorm + ind + wsum). r3 lesson: no runtime-indexed register
// arrays (x2 unroll, named FA/FB sets).
__global__ __launch_bounds__(256, 3) void vq_kernel(const float* __restrict__ z,
                                                    const _Float16* __restrict__ Epk,
                                                    const float* __restrict__ enorm,
                                                    const float* __restrict__ E,
                                                    float* __restrict__ out,
                                                    float* __restrict__ loss) {
    const int t = threadIdx.x;
    const int lane = t & 63;
    const int wave = t >> 6;     // row-wave: rows [wave*32, wave*32+32)
    const int m16 = lane & 15;   // A row within subtile / B,C code col
    const int quad = lane >> 4;  // k-group for A/B; row-group for C

    __shared__ __attribute__((aligned(16))) float s_enorm[NCODES];  // 4 KB
    __shared__ int s_ind[MTILE];
    __shared__ float s_wsum[4];

    // one-time enorm -> LDS (vectorized, 256 thr x 16 B)
    *(float4*)&s_enorm[t * 4] = ((const float4*)enorm)[t];

    // Load step ST's 8 fragment sets (hi+lo x 4 ksteps) from global; each is
    // one coalesced 1 KB global_load_dwordx4 (lane-linear packed layout).
#define LOADF(ST, H, L)                                                              \
    {                                                                                \
        const char* gb = (const char*)Epk + (size_t)(ST)*TILE_BYTES + lane * 16;     \
        H[0] = *(const f16x8*)(gb);                                                  \
        H[1] = *(const f16x8*)(gb + 1024);                                           \
        H[2] = *(const f16x8*)(gb + 2048);                                           \
        H[3] = *(const f16x8*)(gb + 3072);                                           \
        L[0] = *(const f16x8*)(gb + 4096);                                           \
        L[1] = *(const f16x8*)(gb + 5120);                                           \
        L[2] = *(const f16x8*)(gb + 6144);                                           \
        L[3] = *(const f16x8*)(gb + 7168);                                           \
    }

    f16x8 FAh[KSTEPS], FAl[KSTEPS], FBh[KSTEPS], FBl[KSTEPS];
    LOADF(0, FAh, FAl)  // in flight under A-prep below

    // ---- A fragments: this wave's 32 rows, K=128, scaled by -2, f16 hi/lo.
    // A layout (16x16x32): lane holds A[m=lane&15][k=quad*8+j], j=0..7.
    f16x8 Ahi[NSUB][KSTEPS], Alo[NSUB][KSTEPS];
    float znp[NSUB] = {0.f, 0.f};
    const int rowbase = blockIdx.x * MTILE + wave * ROWS_PER_WAVE;
#pragma unroll
    for (int s = 0; s < NSUB; ++s) {
        const int row = rowbase + s * 16 + m16;
        const float* zp = z + (size_t)row * DIM + quad * 8;
#pragma unroll
        for (int ks = 0; ks < KSTEPS; ++ks) {
            float4 v0 = *(const float4*)(zp + ks * 32);
            float4 v1 = *(const float4*)(zp + ks * 32 + 4);
            float zv[8] = {v0.x, v0.y, v0.z, v0.w, v1.x, v1.y, v1.z, v1.w};
#pragma unroll
            for (int j = 0; j < 8; ++j) {
                znp[s] = fmaf(zv[j], zv[j], znp[s]);
                float tt = -2.f * zv[j];
                _Float16 h = (_Float16)tt;
                Ahi[s][ks][j] = h;
                Alo[s][ks][j] = (_Float16)(tt - (float)h);
            }
        }
    }
    // znorm per row, kept in registers: after the two xors every lane holds
    // the full ||z_row||^2 for row s*16 + m16 of this wave.
#pragma unroll
    for (int s = 0; s < NSUB; ++s) {
        znp[s] += __shfl_xor(znp[s], 16, 64);
        znp[s] += __shfl_xor(znp[s], 32, 64);
    }

    float bestv[NSUB][4];
    int besti[NSUB][4];
#pragma unroll
    for (int s = 0; s < NSUB; ++s)
#pragma unroll
        for (int r = 0; r < 4; ++r) {
            bestv[s][r] = FLT_MAX;
            besti[s][r] = 0;
        }

    __syncthreads();  // s_enorm visible (only barrier before the epilogue)

    float eA = s_enorm[m16], eB = 0.f;

    // Step body: 24 MFMAs on current frags (CH,CL,CE); loads for ST+1 into
    // (NH,NL,NE) issue first and land under the MFMA/argmin (no barriers --
    // compiler places the exact vmcnt before first use next step).
#define BODY(ST, CH, CL, CE, NH, NL, NE, DO_NEXT)                                             \
    {                                                                                         \
        if (DO_NEXT) {                                                                        \
            LOADF((ST) + 1, NH, NL)                                                           \
            NE = s_enorm[((ST) + 1) * CODES_PER_TILE + m16];                                  \
        }                                                                                     \
        f32x4 acc0 = {CE, CE, CE, CE}, acc1 = {CE, CE, CE, CE};                               \
        __builtin_amdgcn_s_setprio(1);                                                        \
        _Pragma("unroll") for (int ks = 0; ks < KSTEPS; ++ks) {                               \
            acc0 = __builtin_amdgcn_mfma_f32_16x16x32_f16(Ahi[0][ks], CH[ks], acc0, 0, 0, 0); \
            acc1 = __builtin_amdgcn_mfma_f32_16x16x32_f16(Ahi[1][ks], CH[ks], acc1, 0, 0, 0); \
            acc0 = __builtin_amdgcn_mfma_f32_16x16x32_f16(Ahi[0][ks], CL[ks], acc0, 0, 0, 0); \
            acc1 = __builtin_amdgcn_mfma_f32_16x16x32_f16(Ahi[1][ks], CL[ks], acc1, 0, 0, 0); \
            acc0 = __builtin_amdgcn_mfma_f32_16x16x32_f16(Alo[0][ks], CH[ks], acc0, 0, 0, 0); \
            acc1 = __builtin_amdgcn_mfma_f32_16x16x32_f16(Alo[1][ks], CH[ks], acc1, 0, 0, 0); \
        }                                                                                     \
        __builtin_amdgcn_s_setprio(0);                                                        \
        const int n_ = (ST)*CODES_PER_TILE + m16;                                             \
        /* C layout: col = lane&15 (code), row = quad*4 + r */                                \
        _Pragma("unroll") for (int r = 0; r < 4; ++r) {                                       \
            if (acc0[r] < bestv[0][r]) { bestv[0][r] = acc0[r]; besti[0][r] = n_; }           \
            if (acc1[r] < bestv[1][r]) { bestv[1][r] = acc1[r]; besti[1][r] = n_; }           \
        }                                                                                     \
    }

    for (int st = 0; st < NSTEPS - 2; st += 2) {
        BODY(st, FAh, FAl, eA, FBh, FBl, eB, 1)
        BODY(st + 1, FBh, FBl, eB, FAh, FAl, eA, 1)
    }
    BODY(NSTEPS - 2, FAh, FAl, eA, FBh, FBl, eB, 1)
    BODY(NSTEPS - 1, FBh, FBl, eB, FAh, FAl, eA, 0)
#undef BODY
#undef LOADF

    // ---- in-wave argmin across the 16 m16-lanes (xor butterflies stay
    // in-quad; lexicographic (v,i) merge == global first-index rule; after the
    // butterfly ALL 16 lanes of a group hold the winner)
#pragma unroll
    for (int s = 0; s < NSUB; ++s)
#pragma unroll
        for (int r = 0; r < 4; ++r) {
            float v = bestv[s][r];
            int i = besti[s][r];
#pragma unroll
            for (int m = 1; m <= 8; m <<= 1) {
                float ov = __shfl_xor(v, m, 64);
                int oi = __shfl_xor(i, m, 64);
                if (ov < v || (ov == v && oi < i)) {
                    v = ov;
                    i = oi;
                }
            }
            bestv[s][r] = v;
            besti[s][r] = i;
        }

    // winner lane per quad owns rows quad*4+r (+s*16); loss partial uses
    // znorm shfl'd from the lane whose m16 == quad*4+r.
    float lp = 0.f;
#pragma unroll
    for (int s = 0; s < NSUB; ++s)
#pragma unroll
        for (int r = 0; r < 4; ++r) {
            const float zz = __shfl(znp[s], quad * 4 + r, 16);
            if (m16 == 0) {
                const int row = wave * ROWS_PER_WAVE + s * 16 + quad * 4 + r;
                s_ind[row] = besti[s][r];
                lp += zz + bestv[s][r];  // ||z-E||^2 = ||z||^2 + dist'
            }
        }
    lp += __shfl_xor(lp, 16, 64);  // lanes {0,16,32,48} hold partials
    lp += __shfl_xor(lp, 32, 64);
    if (lane == 0) s_wsum[wave] = lp;
    __syncthreads();
    if (t == 0)
        atomicAdd(loss, (s_wsum[0] + s_wsum[1] + s_wsum[2] + s_wsum[3]) * LOSS_SCALE);

    // ---- gather-write z_q (STE forward == z_q), float4 coalesced, E is L2-hot
    const float4* E4 = (const float4*)E;
    float4* out4 = (float4*)(out + (size_t)blockIdx.x * (MTILE * DIM));
#pragma unroll
    for (int i = 0; i < (MTILE * DIM) / (256 * 4); ++i) {
        const int f = t + i * 256;  // float4 index within tile
        const int r = f >> 5;       // 32 float4 per row
        const int d = f & 31;
        out4[f] = E4[(size_t)s_ind[r] * 32 + d];
    }
}

extern "C" void kernel_launch(void* const* d_in, const int* in_sizes, int n_in,
                              void* d_out, int out_size, void* d_ws, size_t ws_size,
                              hipStream_t stream) {
    const float* z = (const float*)d_in[0];  // [BN,128] fp32
    const float* E = (const float*)d_in[1];  // [1024,128] fp32
    float* out = (float*)d_out;              // [BN*128] z_q + [1] loss
    float* loss = out + (size_t)(out_size - 1);
    _Float16* Epk = (_Float16*)d_ws;                          // 512 KB packed image
    float* enorm = (float*)((char*)d_ws + (size_t)NCODES * DIM * 2 * sizeof(_Float16));  // 4 KB
    const int BN = in_sizes[0] / DIM;

    prep_kernel<<<NCODES, 128, 0, stream>>>(E, Epk, enorm, loss);
    vq_kernel<<<BN / MTILE, 256, 0, stream>>>(z, Epk, enorm, E, out, loss);
}